// Round 15
// baseline (433.615 us; speedup 1.0000x reference)
//
#include <hip/hip_runtime.h>

#define B_ 4
#define V_ 256
#define H_ 128
#define H2_ 64
#define BV_ 1024  // B*V
#define NJQ_ 4    // j-tiles per (b,i) row
#define JT_ 64    // j rows per k2 block
#define G2_ (BV_ * NJQ_)

typedef unsigned short bhalf;  // bf16 bits (internal storage; all I/O fp32)
using bf16x8 = __attribute__((ext_vector_type(8))) short;
using f32x4  = __attribute__((ext_vector_type(4))) float;

__device__ __forceinline__ float bf2f(bhalf u) {
  return __uint_as_float(((unsigned)u) << 16);
}
__device__ __forceinline__ bhalf f2bf(float f) {       // RNE
  unsigned u = __float_as_uint(f);
  return (bhalf)((u + 0x7FFFu + ((u >> 16) & 1u)) >> 16);
}
__device__ __forceinline__ bhalf f2bf_f(float f) {     // fast round (hot paths)
  return (bhalf)((__float_as_uint(f) + 0x8000u) >> 16);
}
__device__ __forceinline__ unsigned pack2(float a, float b) {
  return (unsigned)f2bf(a) | ((unsigned)f2bf(b) << 16);
}
__device__ __forceinline__ unsigned pack2f(float a, float b) {
  return (unsigned)f2bf_f(a) | ((unsigned)f2bf_f(b) << 16);
}
__device__ __forceinline__ void unpack8(uint4 p, float* d) {
  d[0] = bf2f((bhalf)(p.x & 0xffff)); d[1] = bf2f((bhalf)(p.x >> 16));
  d[2] = bf2f((bhalf)(p.y & 0xffff)); d[3] = bf2f((bhalf)(p.y >> 16));
  d[4] = bf2f((bhalf)(p.z & 0xffff)); d[5] = bf2f((bhalf)(p.z >> 16));
  d[6] = bf2f((bhalf)(p.w & 0xffff)); d[7] = bf2f((bhalf)(p.w >> 16));
}

// async 16B global->LDS. lds base wave-uniform; dest = base + lane*16.
__device__ __forceinline__ void gl2lds16(const bhalf* g, bhalf* l) {
  __builtin_amdgcn_global_load_lds(
      (const __attribute__((address_space(1))) unsigned*)g,
      (__attribute__((address_space(3))) unsigned*)l, 16, 0, 0);
}

// Keep the harness-named kernel symbol (not launched).
__global__ void VRPValueNet_66924180407123_kernel() {}

// ---------------- fused setup: zero stats + x embed + layer-0 proj + UeT prep
// + embed coef table ----------------
__global__ void __launch_bounds__(256) k0_all(
    const float* __restrict__ coord, const float* __restrict__ W_node,
    const float* __restrict__ b_node, float* __restrict__ x,
    const float* __restrict__ Ue, bhalf* __restrict__ UeT,
    float* __restrict__ stats, float* __restrict__ out_acc,
    float* __restrict__ cEmb,
    const float* __restrict__ W_eval, const float* __restrict__ b_eval,
    const float* __restrict__ W_ecat, const float* __restrict__ b_ecat,
    const float* __restrict__ Ve, const float* __restrict__ bVe,
    const float* __restrict__ Vn, const float* __restrict__ bVn,
    const float* __restrict__ Un, const float* __restrict__ bUn,
    float2* __restrict__ VV, float* __restrict__ Unx) {
  __shared__ float xs[H_];
  __shared__ float tile[32][H_ + 1];
  const int bi = blockIdx.x, t = threadIdx.x;
  if (bi == 4) {  // zero Sx[3][256] + Se[2][256] + out_acc
#pragma unroll
    for (int i = 0; i < 5; ++i) stats[i * 256 + t] = 0.f;
    if (t < 8) out_acc[t] = 0.f;
  }
  if (bi == 5 && t < H_) {  // embed coef table (wa, wb, bc)
    float wa_ = 0.f, wb_ = 0.f, bc_ = 0.f;
    if (t < H2_) { wa_ = W_eval[t]; wb_ = 0.f; bc_ = b_eval[t]; }
    else { int h2 = t - H2_; wa_ = W_ecat[h2]; wb_ = W_ecat[H2_ + h2]; bc_ = b_ecat[h2]; }
    cEmb[t] = wa_; cEmb[128 + t] = wb_; cEmb[256 + t] = bc_;
  }
  if (t < H_) {
    float c0 = coord[bi * 3 + 0], c1 = coord[bi * 3 + 1], c2 = coord[bi * 3 + 2];
    float a = b_node[t] + c0 * W_node[t] + c1 * W_node[H_ + t] + c2 * W_node[2 * H_ + t];
    x[(size_t)bi * H_ + t] = a;
    xs[t] = a;
  }
  __syncthreads();
  if (t < H_) {  // layer-0 projections
    float av = bVe[t], an = bVn[t], au = bUn[t];
#pragma unroll 8
    for (int k = 0; k < H_; ++k) {
      float xv = xs[k];
      av += xv * Ve[k * H_ + t];
      an += xv * Vn[k * H_ + t];
      au += xv * Un[k * H_ + t];
    }
    size_t o = (size_t)bi * H_ + t;
    VV[o] = make_float2(av, an);
    Unx[o] = au;
  }
  if (bi < 3) {  // UeT[l][h][k] = bf16(Ue[l][k][h]) via LDS bounce
    const float* src = Ue + bi * H_ * H_;
    unsigned* dstU = (unsigned*)(UeT + bi * H_ * H_);
#pragma unroll
    for (int c0 = 0; c0 < H_; c0 += 32) {
      __syncthreads();
#pragma unroll
      for (int i = 0; i < 16; ++i) {     // coalesced read 32 k-rows x 128 h
        int idx = i * 256 + t;
        int kk = idx >> 7, h = idx & 127;
        tile[kk][h] = src[(c0 + kk) * H_ + h];
      }
      __syncthreads();
#pragma unroll
      for (int i = 0; i < 8; ++i) {      // write 16-uint runs per h-row
        int idx = i * 256 + t;
        int h = idx >> 4, uo = idx & 15;
        dstU[h * 64 + (c0 >> 1) + uo] = pack2(tile[uo * 2][h], tile[uo * 2 + 1][h]);
      }
    }
  }
}

// ---------------- MFMA fused edge pass (512 thr, 64-row j-tile) ----------------
// block = (bi, jq): 64 j x 128 h. 8 waves, wave tile 16j x 64h.
// A-tile recomputed in registers each layer (no e buffer):
//   MODE 0: A = embed(inputs);                         writes t0 + stats
//   MODE 1: A = embed + relu(BN0(t0));                 writes t1 + stats
//   MODE 2: A = embed + relu(BN0(t0)) + relu(BN1(t1)); agg only
// B via global_load_lds; coefs from tiny precomputed global tables (L2-hot).
template <int MODE>
__global__ void __launch_bounds__(512, 6) k2_edge(
    const float* __restrict__ xev, const float* __restrict__ xtr,
    const float* __restrict__ xbt, const float* __restrict__ cEmb,
    bhalf* __restrict__ t_out, const bhalf* __restrict__ t0,
    const bhalf* __restrict__ t1,
    const bhalf* __restrict__ UeT_g, const float* __restrict__ bUe,
    const float2* __restrict__ VV,
    const float* __restrict__ cBN0, const float* __restrict__ cBN1,
    float* __restrict__ aggN, float* __restrict__ aggD,
    float* __restrict__ bn_ps, float* __restrict__ bn_ps2) {
  __shared__ __align__(16) bhalf UeT_s[H_ * H_];  // 32 KB B; reused as red after K
  __shared__ __align__(16) bhalf es[JT_ * H_];    // 16 KB; reused as bounce

  const int t = threadIdx.x;
  const int bi = blockIdx.x >> 2;
  const int jq = blockIdx.x & 3;
  const int b = bi >> 8;
  const int lane = t & 63, w = t >> 6;     // w in [0,8)
  const int c = lane & 15, q = lane >> 4;
  const int jw = w & 3, hw = w >> 2;
  const int wbase = t & 448;               // w*64

  // ---- async stage B (UeT 32 KB), source-XOR-swizzled ----
#pragma unroll
  for (int r = 0; r < 4; ++r) {
    int s = r * 512 + t;
    int row = s >> 4, ckL = s & 15;
    gl2lds16(UeT_g + row * H_ + (ckL ^ (row & 15)) * 8,
             &UeT_s[(size_t)(r * 512 + wbase) * 8]);
  }

  // ---- staging: compute A rows in VGPRs, ds_write swizzled ----
  {
    const int ck = t & 15;
    const bool lo = ck < 8;
    float wa[8] = {0, 0, 0, 0, 0, 0, 0, 0}, wb[8] = {0, 0, 0, 0, 0, 0, 0, 0};
    float bc[8] = {0, 0, 0, 0, 0, 0, 0, 0};
    float sc0[8] = {0, 0, 0, 0, 0, 0, 0, 0}, sh0[8] = {0, 0, 0, 0, 0, 0, 0, 0};
    float sc1[8] = {0, 0, 0, 0, 0, 0, 0, 0}, sh1[8] = {0, 0, 0, 0, 0, 0, 0, 0};
    const float4* cE4 = (const float4*)cEmb;
    float4 va0 = cE4[ck * 2], va1 = cE4[ck * 2 + 1];
    float4 vb0 = cE4[32 + ck * 2], vb1 = cE4[32 + ck * 2 + 1];
    float4 vc0 = cE4[64 + ck * 2], vc1 = cE4[64 + ck * 2 + 1];
    wa[0] = va0.x; wa[1] = va0.y; wa[2] = va0.z; wa[3] = va0.w;
    wa[4] = va1.x; wa[5] = va1.y; wa[6] = va1.z; wa[7] = va1.w;
    wb[0] = vb0.x; wb[1] = vb0.y; wb[2] = vb0.z; wb[3] = vb0.w;
    wb[4] = vb1.x; wb[5] = vb1.y; wb[6] = vb1.z; wb[7] = vb1.w;
    bc[0] = vc0.x; bc[1] = vc0.y; bc[2] = vc0.z; bc[3] = vc0.w;
    bc[4] = vc1.x; bc[5] = vc1.y; bc[6] = vc1.z; bc[7] = vc1.w;
    if (MODE >= 1) {
      const float4* cB4 = (const float4*)cBN0;
      float4 s0a = cB4[ck * 2], s0b = cB4[ck * 2 + 1];
      float4 h0a = cB4[32 + ck * 2], h0b = cB4[32 + ck * 2 + 1];
      sc0[0] = s0a.x; sc0[1] = s0a.y; sc0[2] = s0a.z; sc0[3] = s0a.w;
      sc0[4] = s0b.x; sc0[5] = s0b.y; sc0[6] = s0b.z; sc0[7] = s0b.w;
      sh0[0] = h0a.x; sh0[1] = h0a.y; sh0[2] = h0a.z; sh0[3] = h0a.w;
      sh0[4] = h0b.x; sh0[5] = h0b.y; sh0[6] = h0b.z; sh0[7] = h0b.w;
    }
    if (MODE == 2) {
      const float4* cB4 = (const float4*)cBN1;
      float4 s1a = cB4[ck * 2], s1b = cB4[ck * 2 + 1];
      float4 h1a = cB4[32 + ck * 2], h1b = cB4[32 + ck * 2 + 1];
      sc1[0] = s1a.x; sc1[1] = s1a.y; sc1[2] = s1a.z; sc1[3] = s1a.w;
      sc1[4] = s1b.x; sc1[5] = s1b.y; sc1[6] = s1b.z; sc1[7] = s1b.w;
      sh1[0] = h1a.x; sh1[1] = h1a.y; sh1[2] = h1a.z; sh1[3] = h1a.w;
      sh1[4] = h1b.x; sh1[5] = h1b.y; sh1[6] = h1b.z; sh1[7] = h1b.w;
    }
#pragma unroll
    for (int r = 0; r < 2; ++r) {
      int row = r * 32 + (t >> 4);
      size_t ji = (size_t)bi * V_ + jq * JT_ + row;
      float vev = 0.f, vt = 0.f, vb = 0.f;
      if (lo) vev = xev[ji]; else { vt = xtr[ji]; vb = xbt[ji]; }
      float tv0[8] = {0, 0, 0, 0, 0, 0, 0, 0}, tv1[8] = {0, 0, 0, 0, 0, 0, 0, 0};
      if (MODE >= 1) { uint4 p = *(const uint4*)&t0[ji * H_ + ck * 8]; unpack8(p, tv0); }
      if (MODE == 2) { uint4 p = *(const uint4*)&t1[ji * H_ + ck * 8]; unpack8(p, tv1); }
      float v[8];
#pragma unroll
      for (int m = 0; m < 8; ++m) {
        float e0 = lo ? (vev * wa[m] + bc[m]) : (vt * wa[m] + vb * wb[m] + bc[m]);
        if (MODE >= 1) { float u = sc0[m] * tv0[m] + sh0[m]; if (u > 0.f) e0 += u; }
        if (MODE == 2) { float u = sc1[m] * tv1[m] + sh1[m]; if (u > 0.f) e0 += u; }
        v[m] = e0;
      }
      uint4 st;
      st.x = pack2f(v[0], v[1]); st.y = pack2f(v[2], v[3]);
      st.z = pack2f(v[4], v[5]); st.w = pack2f(v[6], v[7]);
      *(uint4*)&es[row * H_ + ((ck ^ (row & 15)) * 8)] = st;
    }
  }

  // ---- cvi + VV_j prefetch ----
  float cvi[4];
#pragma unroll
  for (int n = 0; n < 4; ++n) {
    int h = hw * 64 + n * 16 + c;
    cvi[n] = bUe[h] + VV[(size_t)bi * H_ + h].x;
  }
  float2 vvr[4][4];
  {
    const float2* vvb = VV + ((size_t)b * V_ + jq * JT_ + jw * 16) * H_ + hw * 64;
#pragma unroll
    for (int n = 0; n < 4; ++n)
#pragma unroll
      for (int r = 0; r < 4; ++r)
        vvr[n][r] = vvb[(q * 4 + r) * H_ + n * 16 + c];
  }
  __syncthreads();  // es image + B DMA complete

  // ---- K loop: wave tile 16j x 64h; A from es, B from UeT_s ----
  f32x4 acc[4];
#pragma unroll
  for (int n = 0; n < 4; ++n) acc[n] = {0.f, 0.f, 0.f, 0.f};
#pragma unroll
  for (int k0 = 0; k0 < 4; ++k0) {
    int kc = k0 * 4 + q;
    bf16x8 af = *(const bf16x8*)&es[(jw * 16 + c) * H_ + ((kc ^ c) * 8)];
    bf16x8 bfr[4];
#pragma unroll
    for (int n = 0; n < 4; ++n)
      bfr[n] = *(const bf16x8*)&UeT_s[(hw * 64 + n * 16 + c) * H_ + ((kc ^ c) * 8)];
#pragma unroll
    for (int n = 0; n < 4; ++n)
      acc[n] = __builtin_amdgcn_mfma_f32_16x16x32_bf16(af, bfr[n], acc[n], 0, 0, 0);
  }
  __syncthreads();  // es + UeT_s free for reuse

  // ---- epilogue ----
  float aN[4] = {0, 0, 0, 0}, aD[4] = {0, 0, 0, 0};
  float bS[4] = {0, 0, 0, 0}, bS2[4] = {0, 0, 0, 0};
#pragma unroll
  for (int n = 0; n < 4; ++n) {
#pragma unroll
    for (int r = 0; r < 4; ++r) {
      int j_ip = jw * 16 + q * 4 + r;
      int h = hw * 64 + n * 16 + c;
      float etv = acc[n][r] + cvi[n] + vvr[n][r].x;
      float g = __builtin_amdgcn_rcpf(1.f + __expf(-etv));
      aN[n] += g * vvr[n][r].y; aD[n] += g;
      if (MODE < 2) {
        bS[n] += etv; bS2[n] += etv * etv;
        es[j_ip * H_ + (((h >> 3) ^ (j_ip & 15)) * 8) + (h & 7)] = f2bf_f(etv);
      }
    }
  }
#pragma unroll
  for (int n = 0; n < 4; ++n) {
    aN[n] += __shfl_xor(aN[n], 16);  aN[n] += __shfl_xor(aN[n], 32);
    aD[n] += __shfl_xor(aD[n], 16);  aD[n] += __shfl_xor(aD[n], 32);
    if (MODE < 2) {
      bS[n] += __shfl_xor(bS[n], 16);  bS[n] += __shfl_xor(bS[n], 32);
      bS2[n] += __shfl_xor(bS2[n], 16); bS2[n] += __shfl_xor(bS2[n], 32);
    }
  }
  float* red = (float*)UeT_s;  // 4 arrays x 8 waves x 64 = 8 KB (UeT_s dead)
  if (lane < 16) {
#pragma unroll
    for (int n = 0; n < 4; ++n) {
      int hl = n * 16 + c;
      red[(0 * 8 + w) * 64 + hl] = aN[n];
      red[(1 * 8 + w) * 64 + hl] = aD[n];
      if (MODE < 2) {
        red[(2 * 8 + w) * 64 + hl] = bS[n];
        red[(3 * 8 + w) * 64 + hl] = bS2[n];
      }
    }
  }
  __syncthreads();

  if (MODE < 2) {  // coalesced bounce -> t_out
#pragma unroll
    for (int it = 0; it < 2; ++it) {
      int slot = it * 512 + t;
      int jj = slot >> 4, ck = slot & 15;
      uint4 v = *(const uint4*)&es[jj * H_ + ((ck ^ (jj & 15)) * 8)];
      *(uint4*)&t_out[((size_t)bi * V_ + jq * JT_ + jj) * H_ + ck * 8] = v;
    }
  }
  if (t < H_) {
    int hw2 = t >> 6, hl = t & 63;
    int wb2 = hw2 * 4;
    size_t o = ((size_t)jq * BV_ + bi) * H_ + t;
    float sN = 0, sD = 0, s1 = 0, s2 = 0;
#pragma unroll
    for (int k = 0; k < 4; ++k) {
      sN += red[(0 * 8 + wb2 + k) * 64 + hl];
      sD += red[(1 * 8 + wb2 + k) * 64 + hl];
      if (MODE < 2) {
        s1 += red[(2 * 8 + wb2 + k) * 64 + hl];
        s2 += red[(3 * 8 + wb2 + k) * 64 + hl];
      }
    }
    aggN[o] = sN; aggD[o] = sD;
    if (MODE < 2) { bn_ps[o] = s1; bn_ps2[o] = s2; }
  }
}

// ---------------- kA: coalesced reductions into raw-sum stats ----------------
// blocks 0..63: xtb = Unx + aggN/aggD (16 bi rows each) + x-BN sums -> Sx (atomic)
// blocks 64..127 (DO_E): reduce bn partials (G2_ rows total) -> Se (atomic)
template <bool DO_E>
__global__ void __launch_bounds__(256) kA(
    const float* __restrict__ bn_ps, const float* __restrict__ bn_ps2,
    const float* __restrict__ Unx,
    const float* __restrict__ aggN, const float* __restrict__ aggD,
    float* __restrict__ xtb, float* __restrict__ Sx, float* __restrict__ Se) {
  __shared__ float r1[256], r2[256];
  const int t = threadIdx.x, h = t & 127, half = t >> 7;
  const int blk = blockIdx.x;
  if (blk < 64) {
    float sx = 0.f, sx2 = 0.f;
    const int bib = blk * 16 + half * 8;
#pragma unroll
    for (int s = 0; s < 8; ++s) {
      int bi = bib + s;
      float sN = 0.f, sD = 0.f;
#pragma unroll
      for (int jq = 0; jq < NJQ_; ++jq) {
        size_t o = ((size_t)(jq * BV_ + bi)) * H_ + h;
        sN += aggN[o]; sD += aggD[o];
      }
      float v = Unx[(size_t)bi * H_ + h] + sN / (sD + 1e-20f);
      xtb[(size_t)bi * H_ + h] = v;
      sx += v; sx2 += v * v;
    }
    r1[t] = sx; r2[t] = sx2; __syncthreads();
    if (t < 128) {
      atomicAdd(&Sx[t], r1[t] + r1[t + 128]);
      atomicAdd(&Sx[128 + t], r2[t] + r2[t + 128]);
    }
  } else if (DO_E) {
    const int rb = (blk - 64) * (G2_ / 64) + half * (G2_ / 128);
    float s = 0.f, s2 = 0.f;
#pragma unroll 8
    for (int rr = 0; rr < G2_ / 128; ++rr) {
      size_t o = (size_t)(rb + rr) * H_ + h;
      s += bn_ps[o]; s2 += bn_ps2[o];
    }
    r1[t] = s; r2[t] = s2; __syncthreads();
    if (t < 128) {
      atomicAdd(&Se[t], r1[t] + r1[t + 128]);
      atomicAdd(&Se[128 + t], r2[t] + r2[t + 128]);
    }
  }
}

// ---------------- kB: per-row x update + (next-layer proj | fused readout) -----
// Also (FIN=0, block 0, ctab_out set): build next k2's BN coef table from Se.
template <int FIN>
__global__ void __launch_bounds__(128) kB(
    float* __restrict__ x, const float* __restrict__ xtb,
    const float* __restrict__ Sx,
    const float* __restrict__ g_x, const float* __restrict__ bx_bn,
    const float* __restrict__ Ve, const float* __restrict__ bVe,
    const float* __restrict__ Vn, const float* __restrict__ bVn,
    const float* __restrict__ Un, const float* __restrict__ bUn,
    float2* __restrict__ VV, float* __restrict__ Unx,
    const float* __restrict__ W1, const float* __restrict__ b1,
    const float* __restrict__ W2, const float* __restrict__ b_mlp2,
    float* __restrict__ out_acc, float* __restrict__ out,
    const float* __restrict__ Se_in, const float* __restrict__ ge_in,
    const float* __restrict__ be_in, float* __restrict__ ctab_out) {
  __shared__ float xs[H_];
  __shared__ float red[H_];
  __shared__ int lastf;
  const int bi = blockIdx.x, h = threadIdx.x;
  if (FIN == 0) {
    if (ctab_out != 0 && bi == 0) {  // BN coef table for next k2
      const float inv = 1.f / 262144.f;
      float mu = Se_in[h] * inv;
      float var = Se_in[128 + h] * inv - mu * mu;
      float rs = rsqrtf(var + 1e-5f);
      float s = ge_in[h] * rs;
      ctab_out[h] = s;
      ctab_out[128 + h] = be_in[h] - s * mu;
    }
  }
  {
    float S = Sx[h], S2 = Sx[128 + h];
    float mu = S * (1.f / 1024.f);
    float var = S2 * (1.f / 1024.f) - mu * mu;
    float rs = rsqrtf(var + 1e-5f);
    float g = g_x[h], bb = bx_bn[h];
    float xv = x[(size_t)bi * H_ + h];
    float v = g * (xtb[(size_t)bi * H_ + h] - mu) * rs + bb;
    if (v > 0.f) xv += v;
    if (FIN == 0) x[(size_t)bi * H_ + h] = xv;
    xs[h] = xv;
  }
  __syncthreads();
  if (FIN == 0) {
    float av = bVe[h], an = bVn[h], au = bUn[h];
#pragma unroll 8
    for (int k = 0; k < H_; ++k) {
      float xv = xs[k];
      av += xv * Ve[k * H_ + h];
      an += xv * Vn[k * H_ + h];
      au += xv * Un[k * H_ + h];
    }
    size_t o = (size_t)bi * H_ + h;
    VV[o] = make_float2(av, an);
    Unx[o] = au;
  } else {
    const int b = bi >> 8;
    float a = b1[h];
#pragma unroll 8
    for (int k = 0; k < H_; ++k) a += xs[k] * W1[k * H_ + h];
    a = fmaxf(a, 0.f) * W2[h];
    red[h] = a; __syncthreads();
    for (int s = 64; s > 0; s >>= 1) {
      if (h < s) red[h] += red[h + s];
      __syncthreads();
    }
    if (h == 0) {
      atomicAdd(&out_acc[b], red[0]);
      __threadfence();
      lastf = (atomicAdd((int*)&out_acc[4], 1) == BV_ - 1) ? 1 : 0;
    }
    __syncthreads();
    if (lastf && h < 4) {
      float v = atomicAdd(&out_acc[h], 0.f);  // coherent read
      out[h] = v * (1.f / 256.f) + b_mlp2[0];
    }
  }
}

extern "C" void kernel_launch(void* const* d_in, const int* in_sizes, int n_in,
                              void* d_out, int out_size, void* d_ws, size_t ws_size,
                              hipStream_t stream) {
  (void)in_sizes; (void)out_size; (void)ws_size;
  const int off = n_in - 26;  // tolerate pruned x_edges
  const float* x_ev    = (const float*)d_in[off + 0];
  const float* x_coord = (const float*)d_in[off + 1];
  const float* x_tour  = (const float*)d_in[off + 2];
  const float* x_btour = (const float*)d_in[off + 3];
  const float* W_node  = (const float*)d_in[off + 4];
  const float* b_node  = (const float*)d_in[off + 5];
  const float* W_eval  = (const float*)d_in[off + 6];
  const float* b_eval  = (const float*)d_in[off + 7];
  const float* W_ecat  = (const float*)d_in[off + 8];
  const float* b_ecat  = (const float*)d_in[off + 9];
  const float* Ue      = (const float*)d_in[off + 10];
  const float* bUe     = (const float*)d_in[off + 11];
  const float* Ve      = (const float*)d_in[off + 12];
  const float* bVe     = (const float*)d_in[off + 13];
  const float* Un      = (const float*)d_in[off + 14];
  const float* bUn     = (const float*)d_in[off + 15];
  const float* Vn      = (const float*)d_in[off + 16];
  const float* bVn     = (const float*)d_in[off + 17];
  const float* g_e     = (const float*)d_in[off + 18];
  const float* be_bn   = (const float*)d_in[off + 19];
  const float* g_x     = (const float*)d_in[off + 20];
  const float* bx_bn   = (const float*)d_in[off + 21];
  const float* W_mlp1  = (const float*)d_in[off + 22];
  const float* b_mlp1  = (const float*)d_in[off + 23];
  const float* W_mlp2  = (const float*)d_in[off + 24];
  const float* b_mlp2  = (const float*)d_in[off + 25];

  char* ws = (char*)d_ws;
  float*  x       = (float*)(ws + 0x0000000);
  float2* VV      = (float2*)(ws + 0x0080000);   // 1 MB
  float*  Unx     = (float*)(ws + 0x0180000);    // 512 KB
  float*  aggN    = (float*)(ws + 0x0200000);    // [NJQ][BV][H]
  float*  aggD    = (float*)(ws + 0x0600000);
  float*  bn_ps   = (float*)(ws + 0x0A00000);    // [G2][H]
  float*  bn_ps2  = (float*)(ws + 0x0E00000);
  float*  xtb     = (float*)(ws + 0x1200000);    // 512 KB
  float*  stats   = (float*)(ws + 0x1280000);    // Sx[3][256]+Se[2][256]+coef tables
  float*  out_acc = (float*)(ws + 0x1284000);
  bhalf*  UeT_g   = (bhalf*)(ws + 0x1290000);    // 96 KB
  bhalf*  t0      = (bhalf*)(ws + 0x1300000);                 // 64 MiB
  bhalf*  t1      = (bhalf*)(ws + 0x1300000 + 0x4000000);     // 64 MiB
  float*  Sx0 = stats;
  float*  Sx1 = stats + 256;
  float*  Sx2 = stats + 512;
  float*  Se0 = stats + 768;
  float*  Se1 = stats + 1024;
  float*  cEmb = stats + 1280;   // 384 floats: wa, wb, bc
  float*  cBN0 = stats + 1664;   // 256: sc0, sh0
  float*  cBN1 = stats + 1920;   // 256: sc1, sh1

  k0_all<<<BV_, 256, 0, stream>>>(x_coord, W_node, b_node, x, Ue, UeT_g,
                                  stats, out_acc, cEmb,
                                  W_eval, b_eval, W_ecat, b_ecat,
                                  Ve, bVe, Vn, bVn, Un, bUn, VV, Unx);

  // ---- layer 0 ----
  k2_edge<0><<<G2_, 512, 0, stream>>>(x_ev, x_tour, x_btour, cEmb,
                                      t0, (bhalf*)0, (bhalf*)0,
                                      UeT_g, bUe, VV, (float*)0, (float*)0,
                                      aggN, aggD, bn_ps, bn_ps2);
  kA<true><<<128, 256, 0, stream>>>(bn_ps, bn_ps2, Unx, aggN, aggD, xtb, Sx0, Se0);
  kB<0><<<BV_, 128, 0, stream>>>(x, xtb, Sx0, g_x, bx_bn,
                                 Ve + H_*H_, bVe + H_, Vn + H_*H_, bVn + H_,
                                 Un + H_*H_, bUn + H_, VV, Unx,
                                 (float*)0, (float*)0, (float*)0, (float*)0,
                                 out_acc, (float*)d_out,
                                 Se0, g_e, be_bn, cBN0);
  // ---- layer 1 ----
  k2_edge<1><<<G2_, 512, 0, stream>>>(x_ev, x_tour, x_btour, cEmb,
                                      t1, t0, (bhalf*)0,
                                      UeT_g + H_*H_, bUe + H_, VV, cBN0, (float*)0,
                                      aggN, aggD, bn_ps, bn_ps2);
  kA<true><<<128, 256, 0, stream>>>(bn_ps, bn_ps2, Unx, aggN, aggD, xtb, Sx1, Se1);
  kB<0><<<BV_, 128, 0, stream>>>(x, xtb, Sx1, g_x + H_, bx_bn + H_,
                                 Ve + 2*H_*H_, bVe + 2*H_, Vn + 2*H_*H_, bVn + 2*H_,
                                 Un + 2*H_*H_, bUn + 2*H_, VV, Unx,
                                 (float*)0, (float*)0, (float*)0, (float*)0,
                                 out_acc, (float*)d_out,
                                 Se1, g_e + H_, be_bn + H_, cBN1);
  // ---- layer 2 ----
  k2_edge<2><<<G2_, 512, 0, stream>>>(x_ev, x_tour, x_btour, cEmb,
                                      (bhalf*)0, t0, t1,
                                      UeT_g + 2*H_*H_, bUe + 2*H_, VV, cBN0, cBN1,
                                      aggN, aggD, bn_ps, bn_ps2);
  kA<false><<<64, 256, 0, stream>>>(bn_ps, bn_ps2, Unx, aggN, aggD, xtb, Sx2, Se0);
  kB<1><<<BV_, 128, 0, stream>>>(x, xtb, Sx2, g_x + 2*H_, bx_bn + 2*H_,
                                 (float*)0, (float*)0, (float*)0, (float*)0,
                                 (float*)0, (float*)0, VV, Unx,
                                 W_mlp1, b_mlp1, W_mlp2, b_mlp2,
                                 out_acc, (float*)d_out,
                                 (float*)0, (float*)0, (float*)0, (float*)0);
}

// Round 16
// 347.883 us; speedup vs baseline: 1.2464x; 1.2464x over previous
//
#include <hip/hip_runtime.h>

#define B_ 4
#define V_ 256
#define H_ 128
#define H2_ 64
#define BV_ 1024  // B*V
#define NJQ_ 8    // j-tiles per (b,i) row
#define JT_ 32    // j rows per k2 block

typedef unsigned short bhalf;  // bf16 bits (internal storage; all I/O fp32)
using bf16x8 = __attribute__((ext_vector_type(8))) short;
using f32x4  = __attribute__((ext_vector_type(4))) float;

__device__ __forceinline__ float bf2f(bhalf u) {
  return __uint_as_float(((unsigned)u) << 16);
}
__device__ __forceinline__ bhalf f2bf(float f) {       // RNE
  unsigned u = __float_as_uint(f);
  return (bhalf)((u + 0x7FFFu + ((u >> 16) & 1u)) >> 16);
}
__device__ __forceinline__ bhalf f2bf_f(float f) {     // fast round (hot paths)
  return (bhalf)((__float_as_uint(f) + 0x8000u) >> 16);
}
__device__ __forceinline__ unsigned pack2(float a, float b) {
  return (unsigned)f2bf(a) | ((unsigned)f2bf(b) << 16);
}
__device__ __forceinline__ unsigned pack2f(float a, float b) {
  return (unsigned)f2bf_f(a) | ((unsigned)f2bf_f(b) << 16);
}
__device__ __forceinline__ void unpack8(uint4 p, float* d) {
  d[0] = bf2f((bhalf)(p.x & 0xffff)); d[1] = bf2f((bhalf)(p.x >> 16));
  d[2] = bf2f((bhalf)(p.y & 0xffff)); d[3] = bf2f((bhalf)(p.y >> 16));
  d[4] = bf2f((bhalf)(p.z & 0xffff)); d[5] = bf2f((bhalf)(p.z >> 16));
  d[6] = bf2f((bhalf)(p.w & 0xffff)); d[7] = bf2f((bhalf)(p.w >> 16));
}

// async 16B global->LDS. lds base wave-uniform; dest = base + lane*16.
__device__ __forceinline__ void gl2lds16(const bhalf* g, bhalf* l) {
  __builtin_amdgcn_global_load_lds(
      (const __attribute__((address_space(1))) unsigned*)g,
      (__attribute__((address_space(3))) unsigned*)l, 16, 0, 0);
}

// Keep the harness-named kernel symbol (not launched).
__global__ void VRPValueNet_66924180407123_kernel() {}

// ---------------- fused setup: zero stats + x embed + layer-0 proj + UeT prep
// + embed coef table ----------------
__global__ void __launch_bounds__(256) k0_all(
    const float* __restrict__ coord, const float* __restrict__ W_node,
    const float* __restrict__ b_node, float* __restrict__ x,
    const float* __restrict__ Ue, bhalf* __restrict__ UeT,
    float* __restrict__ stats, float* __restrict__ out_acc,
    float* __restrict__ cEmb,
    const float* __restrict__ W_eval, const float* __restrict__ b_eval,
    const float* __restrict__ W_ecat, const float* __restrict__ b_ecat,
    const float* __restrict__ Ve, const float* __restrict__ bVe,
    const float* __restrict__ Vn, const float* __restrict__ bVn,
    const float* __restrict__ Un, const float* __restrict__ bUn,
    float2* __restrict__ VV, float* __restrict__ Unx) {
  __shared__ float xs[H_];
  __shared__ float tile[32][H_ + 1];
  const int bi = blockIdx.x, t = threadIdx.x;
  if (bi == 4) {  // zero Sx[3][256] + Se[2][256] + out_acc
#pragma unroll
    for (int i = 0; i < 5; ++i) stats[i * 256 + t] = 0.f;
    if (t < 8) out_acc[t] = 0.f;
  }
  if (bi == 5 && t < H_) {  // embed coef table (wa, wb, bc)
    float wa_ = 0.f, wb_ = 0.f, bc_ = 0.f;
    if (t < H2_) { wa_ = W_eval[t]; wb_ = 0.f; bc_ = b_eval[t]; }
    else { int h2 = t - H2_; wa_ = W_ecat[h2]; wb_ = W_ecat[H2_ + h2]; bc_ = b_ecat[h2]; }
    cEmb[t] = wa_; cEmb[128 + t] = wb_; cEmb[256 + t] = bc_;
  }
  if (t < H_) {
    float c0 = coord[bi * 3 + 0], c1 = coord[bi * 3 + 1], c2 = coord[bi * 3 + 2];
    float a = b_node[t] + c0 * W_node[t] + c1 * W_node[H_ + t] + c2 * W_node[2 * H_ + t];
    x[(size_t)bi * H_ + t] = a;
    xs[t] = a;
  }
  __syncthreads();
  if (t < H_) {  // layer-0 projections
    float av = bVe[t], an = bVn[t], au = bUn[t];
#pragma unroll 8
    for (int k = 0; k < H_; ++k) {
      float xv = xs[k];
      av += xv * Ve[k * H_ + t];
      an += xv * Vn[k * H_ + t];
      au += xv * Un[k * H_ + t];
    }
    size_t o = (size_t)bi * H_ + t;
    VV[o] = make_float2(av, an);
    Unx[o] = au;
  }
  if (bi < 3) {  // UeT[l][h][k] = bf16(Ue[l][k][h]) via LDS bounce
    const float* src = Ue + bi * H_ * H_;
    unsigned* dstU = (unsigned*)(UeT + bi * H_ * H_);
#pragma unroll
    for (int c0 = 0; c0 < H_; c0 += 32) {
      __syncthreads();
#pragma unroll
      for (int i = 0; i < 16; ++i) {     // coalesced read 32 k-rows x 128 h
        int idx = i * 256 + t;
        int kk = idx >> 7, h = idx & 127;
        tile[kk][h] = src[(c0 + kk) * H_ + h];
      }
      __syncthreads();
#pragma unroll
      for (int i = 0; i < 8; ++i) {      // write 16-uint runs per h-row
        int idx = i * 256 + t;
        int h = idx >> 4, uo = idx & 15;
        dstU[h * 64 + (c0 >> 1) + uo] = pack2(tile[uo * 2][h], tile[uo * 2 + 1][h]);
      }
    }
  }
}

// ---------------- MFMA fused edge pass ----------------
// block = (bi, jq): 32 j x 128 h. 4 waves, wave tile 16j x 64h.
// A-tile recomputed in registers each layer (no e buffer):
//   MODE 0: A = embed(inputs);                         writes t0 + stats
//   MODE 1: A = embed + relu(BN0(t0));                 writes t1 + stats
//   MODE 2: A = embed + relu(BN0(t0)) + relu(BN1(t1)); agg only
// B via global_load_lds; coefs from tiny precomputed global tables (L2-hot).
template <int MODE>
__global__ void __launch_bounds__(256, 4) k2_edge(
    const float* __restrict__ xev, const float* __restrict__ xtr,
    const float* __restrict__ xbt, const float* __restrict__ cEmb,
    bhalf* __restrict__ t_out, const bhalf* __restrict__ t0,
    const bhalf* __restrict__ t1,
    const bhalf* __restrict__ UeT_g, const float* __restrict__ bUe,
    const float2* __restrict__ VV,
    const float* __restrict__ cBN0, const float* __restrict__ cBN1,
    float* __restrict__ aggN, float* __restrict__ aggD,
    float* __restrict__ bn_ps, float* __restrict__ bn_ps2) {
  __shared__ __align__(16) bhalf UeT_s[H_ * H_];  // 32 KB B; reused as red after K
  __shared__ __align__(16) bhalf es[JT_ * H_];    // 8 KB A-tile; reused as bounce

  const int t = threadIdx.x;
  const int bi = blockIdx.x >> 3;
  const int jq = blockIdx.x & 7;
  const int b = bi >> 8;
  const int lane = t & 63, w = t >> 6;
  const int c = lane & 15, q = lane >> 4;
  const int jw = w & 1, hw = w >> 1;
  const int wbase = t & 192;  // w*64

  // ---- async stage B (UeT 32 KB), source-XOR-swizzled ----
#pragma unroll
  for (int r = 0; r < 8; ++r) {
    int s = r * 256 + t;
    int row = s >> 4, ckL = s & 15;
    gl2lds16(UeT_g + row * H_ + (ckL ^ (row & 15)) * 8,
             &UeT_s[(size_t)(r * 256 + wbase) * 8]);
  }

  // ---- staging: compute A rows in VGPRs, ds_write swizzled ----
  {
    const int ck = t & 15;
    const bool lo = ck < 8;
    float wa[8] = {0, 0, 0, 0, 0, 0, 0, 0}, wb[8] = {0, 0, 0, 0, 0, 0, 0, 0};
    float bc[8] = {0, 0, 0, 0, 0, 0, 0, 0};
    float sc0[8] = {0, 0, 0, 0, 0, 0, 0, 0}, sh0[8] = {0, 0, 0, 0, 0, 0, 0, 0};
    float sc1[8] = {0, 0, 0, 0, 0, 0, 0, 0}, sh1[8] = {0, 0, 0, 0, 0, 0, 0, 0};
    const float4* cE4 = (const float4*)cEmb;
    float4 va0 = cE4[ck * 2], va1 = cE4[ck * 2 + 1];
    float4 vb0 = cE4[32 + ck * 2], vb1 = cE4[32 + ck * 2 + 1];
    float4 vc0 = cE4[64 + ck * 2], vc1 = cE4[64 + ck * 2 + 1];
    wa[0] = va0.x; wa[1] = va0.y; wa[2] = va0.z; wa[3] = va0.w;
    wa[4] = va1.x; wa[5] = va1.y; wa[6] = va1.z; wa[7] = va1.w;
    wb[0] = vb0.x; wb[1] = vb0.y; wb[2] = vb0.z; wb[3] = vb0.w;
    wb[4] = vb1.x; wb[5] = vb1.y; wb[6] = vb1.z; wb[7] = vb1.w;
    bc[0] = vc0.x; bc[1] = vc0.y; bc[2] = vc0.z; bc[3] = vc0.w;
    bc[4] = vc1.x; bc[5] = vc1.y; bc[6] = vc1.z; bc[7] = vc1.w;
    if (MODE >= 1) {
      const float4* cB4 = (const float4*)cBN0;
      float4 s0a = cB4[ck * 2], s0b = cB4[ck * 2 + 1];
      float4 h0a = cB4[32 + ck * 2], h0b = cB4[32 + ck * 2 + 1];
      sc0[0] = s0a.x; sc0[1] = s0a.y; sc0[2] = s0a.z; sc0[3] = s0a.w;
      sc0[4] = s0b.x; sc0[5] = s0b.y; sc0[6] = s0b.z; sc0[7] = s0b.w;
      sh0[0] = h0a.x; sh0[1] = h0a.y; sh0[2] = h0a.z; sh0[3] = h0a.w;
      sh0[4] = h0b.x; sh0[5] = h0b.y; sh0[6] = h0b.z; sh0[7] = h0b.w;
    }
    if (MODE == 2) {
      const float4* cB4 = (const float4*)cBN1;
      float4 s1a = cB4[ck * 2], s1b = cB4[ck * 2 + 1];
      float4 h1a = cB4[32 + ck * 2], h1b = cB4[32 + ck * 2 + 1];
      sc1[0] = s1a.x; sc1[1] = s1a.y; sc1[2] = s1a.z; sc1[3] = s1a.w;
      sc1[4] = s1b.x; sc1[5] = s1b.y; sc1[6] = s1b.z; sc1[7] = s1b.w;
      sh1[0] = h1a.x; sh1[1] = h1a.y; sh1[2] = h1a.z; sh1[3] = h1a.w;
      sh1[4] = h1b.x; sh1[5] = h1b.y; sh1[6] = h1b.z; sh1[7] = h1b.w;
    }
#pragma unroll
    for (int r = 0; r < 2; ++r) {
      int row = r * 16 + (t >> 4);
      size_t ji = (size_t)bi * V_ + jq * JT_ + row;
      float vev = 0.f, vt = 0.f, vb = 0.f;
      if (lo) vev = xev[ji]; else { vt = xtr[ji]; vb = xbt[ji]; }
      float tv0[8] = {0, 0, 0, 0, 0, 0, 0, 0}, tv1[8] = {0, 0, 0, 0, 0, 0, 0, 0};
      if (MODE >= 1) { uint4 p = *(const uint4*)&t0[ji * H_ + ck * 8]; unpack8(p, tv0); }
      if (MODE == 2) { uint4 p = *(const uint4*)&t1[ji * H_ + ck * 8]; unpack8(p, tv1); }
      float v[8];
#pragma unroll
      for (int m = 0; m < 8; ++m) {
        float e0 = lo ? (vev * wa[m] + bc[m]) : (vt * wa[m] + vb * wb[m] + bc[m]);
        if (MODE >= 1) { float u = sc0[m] * tv0[m] + sh0[m]; if (u > 0.f) e0 += u; }
        if (MODE == 2) { float u = sc1[m] * tv1[m] + sh1[m]; if (u > 0.f) e0 += u; }
        v[m] = e0;
      }
      uint4 st;
      st.x = pack2f(v[0], v[1]); st.y = pack2f(v[2], v[3]);
      st.z = pack2f(v[4], v[5]); st.w = pack2f(v[6], v[7]);
      *(uint4*)&es[row * H_ + ((ck ^ (row & 15)) * 8)] = st;
    }
  }

  // ---- cvi + VV_j prefetch ----
  float cvi[4];
#pragma unroll
  for (int n = 0; n < 4; ++n) {
    int h = hw * 64 + n * 16 + c;
    cvi[n] = bUe[h] + VV[(size_t)bi * H_ + h].x;
  }
  float2 vvr[4][4];
  {
    const float2* vvb = VV + ((size_t)b * V_ + jq * JT_ + jw * 16) * H_ + hw * 64;
#pragma unroll
    for (int n = 0; n < 4; ++n)
#pragma unroll
      for (int r = 0; r < 4; ++r)
        vvr[n][r] = vvb[(q * 4 + r) * H_ + n * 16 + c];
  }
  __syncthreads();  // es image + B DMA complete

  // ---- K loop: wave tile 16j x 64h; A from es, B from UeT_s ----
  f32x4 acc[4];
#pragma unroll
  for (int n = 0; n < 4; ++n) acc[n] = {0.f, 0.f, 0.f, 0.f};
#pragma unroll
  for (int k0 = 0; k0 < 4; ++k0) {
    int kc = k0 * 4 + q;
    bf16x8 af = *(const bf16x8*)&es[(jw * 16 + c) * H_ + ((kc ^ c) * 8)];
    bf16x8 bfr[4];
#pragma unroll
    for (int n = 0; n < 4; ++n)
      bfr[n] = *(const bf16x8*)&UeT_s[(hw * 64 + n * 16 + c) * H_ + ((kc ^ c) * 8)];
#pragma unroll
    for (int n = 0; n < 4; ++n)
      acc[n] = __builtin_amdgcn_mfma_f32_16x16x32_bf16(af, bfr[n], acc[n], 0, 0, 0);
  }
  __syncthreads();  // es + UeT_s free for reuse

  // ---- epilogue ----
  float aN[4] = {0, 0, 0, 0}, aD[4] = {0, 0, 0, 0};
  float bS[4] = {0, 0, 0, 0}, bS2[4] = {0, 0, 0, 0};
#pragma unroll
  for (int n = 0; n < 4; ++n) {
#pragma unroll
    for (int r = 0; r < 4; ++r) {
      int j_ip = jw * 16 + q * 4 + r;
      int h = hw * 64 + n * 16 + c;
      float etv = acc[n][r] + cvi[n] + vvr[n][r].x;
      float g = __builtin_amdgcn_rcpf(1.f + __expf(-etv));
      aN[n] += g * vvr[n][r].y; aD[n] += g;
      if (MODE < 2) {
        bS[n] += etv; bS2[n] += etv * etv;
        es[j_ip * H_ + (((h >> 3) ^ (j_ip & 15)) * 8) + (h & 7)] = f2bf_f(etv);
      }
    }
  }
#pragma unroll
  for (int n = 0; n < 4; ++n) {
    aN[n] += __shfl_xor(aN[n], 16);  aN[n] += __shfl_xor(aN[n], 32);
    aD[n] += __shfl_xor(aD[n], 16);  aD[n] += __shfl_xor(aD[n], 32);
    if (MODE < 2) {
      bS[n] += __shfl_xor(bS[n], 16);  bS[n] += __shfl_xor(bS[n], 32);
      bS2[n] += __shfl_xor(bS2[n], 16); bS2[n] += __shfl_xor(bS2[n], 32);
    }
  }
  float* red = (float*)UeT_s;  // UeT_s dead after K-loop
  if (lane < 16) {
#pragma unroll
    for (int n = 0; n < 4; ++n) {
      int hl = n * 16 + c;
      red[(0 * 4 + w) * 64 + hl] = aN[n];
      red[(1 * 4 + w) * 64 + hl] = aD[n];
      if (MODE < 2) {
        red[(2 * 4 + w) * 64 + hl] = bS[n];
        red[(3 * 4 + w) * 64 + hl] = bS2[n];
      }
    }
  }
  __syncthreads();

  if (MODE < 2) {  // coalesced bounce -> t_out
#pragma unroll
    for (int it = 0; it < 2; ++it) {
      int slot = it * 256 + t;
      int jj = slot >> 4, ck = slot & 15;
      uint4 v = *(const uint4*)&es[jj * H_ + ((ck ^ (jj & 15)) * 8)];
      *(uint4*)&t_out[((size_t)bi * V_ + jq * JT_ + jj) * H_ + ck * 8] = v;
    }
  }
  if (t < H_) {
    int hw2 = t >> 6, hl = t & 63;
    int w0 = hw2 * 2, w1 = w0 + 1;
    size_t o = ((size_t)jq * BV_ + bi) * H_ + t;
    aggN[o] = red[(0 * 4 + w0) * 64 + hl] + red[(0 * 4 + w1) * 64 + hl];
    aggD[o] = red[(1 * 4 + w0) * 64 + hl] + red[(1 * 4 + w1) * 64 + hl];
    if (MODE < 2) {
      bn_ps[o]  = red[(2 * 4 + w0) * 64 + hl] + red[(2 * 4 + w1) * 64 + hl];
      bn_ps2[o] = red[(3 * 4 + w0) * 64 + hl] + red[(3 * 4 + w1) * 64 + hl];
    }
  }
}

// ---------------- kA: coalesced reductions into raw-sum stats ----------------
// blocks 0..63: xtb = Unx + aggN/aggD (16 bi rows each) + x-BN sums -> Sx (atomic)
// blocks 64..127 (DO_E): reduce bn partials (128 rows each) -> Se (atomic)
template <bool DO_E>
__global__ void __launch_bounds__(256) kA(
    const float* __restrict__ bn_ps, const float* __restrict__ bn_ps2,
    const float* __restrict__ Unx,
    const float* __restrict__ aggN, const float* __restrict__ aggD,
    float* __restrict__ xtb, float* __restrict__ Sx, float* __restrict__ Se) {
  __shared__ float r1[256], r2[256];
  const int t = threadIdx.x, h = t & 127, half = t >> 7;
  const int blk = blockIdx.x;
  if (blk < 64) {
    float sx = 0.f, sx2 = 0.f;
    const int bib = blk * 16 + half * 8;
#pragma unroll
    for (int s = 0; s < 8; ++s) {
      int bi = bib + s;
      float sN = 0.f, sD = 0.f;
#pragma unroll
      for (int jq = 0; jq < NJQ_; ++jq) {
        size_t o = ((size_t)(jq * BV_ + bi)) * H_ + h;
        sN += aggN[o]; sD += aggD[o];
      }
      float v = Unx[(size_t)bi * H_ + h] + sN / (sD + 1e-20f);
      xtb[(size_t)bi * H_ + h] = v;
      sx += v; sx2 += v * v;
    }
    r1[t] = sx; r2[t] = sx2; __syncthreads();
    if (t < 128) {
      atomicAdd(&Sx[t], r1[t] + r1[t + 128]);
      atomicAdd(&Sx[128 + t], r2[t] + r2[t + 128]);
    }
  } else if (DO_E) {
    const int rb = (blk - 64) * 128 + half * 64;
    float s = 0.f, s2 = 0.f;
#pragma unroll 8
    for (int rr = 0; rr < 64; ++rr) {
      size_t o = (size_t)(rb + rr) * H_ + h;
      s += bn_ps[o]; s2 += bn_ps2[o];
    }
    r1[t] = s; r2[t] = s2; __syncthreads();
    if (t < 128) {
      atomicAdd(&Se[t], r1[t] + r1[t + 128]);
      atomicAdd(&Se[128 + t], r2[t] + r2[t + 128]);
    }
  }
}

// ---------------- kB: per-row x update + (next-layer proj | fused readout) -----
// Also (FIN=0, block 0, ctab_out set): build next k2's BN coef table from Se.
template <int FIN>
__global__ void __launch_bounds__(128) kB(
    float* __restrict__ x, const float* __restrict__ xtb,
    const float* __restrict__ Sx,
    const float* __restrict__ g_x, const float* __restrict__ bx_bn,
    const float* __restrict__ Ve, const float* __restrict__ bVe,
    const float* __restrict__ Vn, const float* __restrict__ bVn,
    const float* __restrict__ Un, const float* __restrict__ bUn,
    float2* __restrict__ VV, float* __restrict__ Unx,
    const float* __restrict__ W1, const float* __restrict__ b1,
    const float* __restrict__ W2, const float* __restrict__ b_mlp2,
    float* __restrict__ out_acc, float* __restrict__ out,
    const float* __restrict__ Se_in, const float* __restrict__ ge_in,
    const float* __restrict__ be_in, float* __restrict__ ctab_out) {
  __shared__ float xs[H_];
  __shared__ float red[H_];
  __shared__ int lastf;
  const int bi = blockIdx.x, h = threadIdx.x;
  if (FIN == 0) {
    if (ctab_out != 0 && bi == 0) {  // BN coef table for next k2
      const float inv = 1.f / 262144.f;
      float mu = Se_in[h] * inv;
      float var = Se_in[128 + h] * inv - mu * mu;
      float rs = rsqrtf(var + 1e-5f);
      float s = ge_in[h] * rs;
      ctab_out[h] = s;
      ctab_out[128 + h] = be_in[h] - s * mu;
    }
  }
  {
    float S = Sx[h], S2 = Sx[128 + h];
    float mu = S * (1.f / 1024.f);
    float var = S2 * (1.f / 1024.f) - mu * mu;
    float rs = rsqrtf(var + 1e-5f);
    float g = g_x[h], bb = bx_bn[h];
    float xv = x[(size_t)bi * H_ + h];
    float v = g * (xtb[(size_t)bi * H_ + h] - mu) * rs + bb;
    if (v > 0.f) xv += v;
    if (FIN == 0) x[(size_t)bi * H_ + h] = xv;
    xs[h] = xv;
  }
  __syncthreads();
  if (FIN == 0) {
    float av = bVe[h], an = bVn[h], au = bUn[h];
#pragma unroll 8
    for (int k = 0; k < H_; ++k) {
      float xv = xs[k];
      av += xv * Ve[k * H_ + h];
      an += xv * Vn[k * H_ + h];
      au += xv * Un[k * H_ + h];
    }
    size_t o = (size_t)bi * H_ + h;
    VV[o] = make_float2(av, an);
    Unx[o] = au;
  } else {
    const int b = bi >> 8;
    float a = b1[h];
#pragma unroll 8
    for (int k = 0; k < H_; ++k) a += xs[k] * W1[k * H_ + h];
    a = fmaxf(a, 0.f) * W2[h];
    red[h] = a; __syncthreads();
    for (int s = 64; s > 0; s >>= 1) {
      if (h < s) red[h] += red[h + s];
      __syncthreads();
    }
    if (h == 0) {
      atomicAdd(&out_acc[b], red[0]);
      __threadfence();
      lastf = (atomicAdd((int*)&out_acc[4], 1) == BV_ - 1) ? 1 : 0;
    }
    __syncthreads();
    if (lastf && h < 4) {
      float v = atomicAdd(&out_acc[h], 0.f);  // coherent read
      out[h] = v * (1.f / 256.f) + b_mlp2[0];
    }
  }
}

extern "C" void kernel_launch(void* const* d_in, const int* in_sizes, int n_in,
                              void* d_out, int out_size, void* d_ws, size_t ws_size,
                              hipStream_t stream) {
  (void)in_sizes; (void)out_size; (void)ws_size;
  const int off = n_in - 26;  // tolerate pruned x_edges
  const float* x_ev    = (const float*)d_in[off + 0];
  const float* x_coord = (const float*)d_in[off + 1];
  const float* x_tour  = (const float*)d_in[off + 2];
  const float* x_btour = (const float*)d_in[off + 3];
  const float* W_node  = (const float*)d_in[off + 4];
  const float* b_node  = (const float*)d_in[off + 5];
  const float* W_eval  = (const float*)d_in[off + 6];
  const float* b_eval  = (const float*)d_in[off + 7];
  const float* W_ecat  = (const float*)d_in[off + 8];
  const float* b_ecat  = (const float*)d_in[off + 9];
  const float* Ue      = (const float*)d_in[off + 10];
  const float* bUe     = (const float*)d_in[off + 11];
  const float* Ve      = (const float*)d_in[off + 12];
  const float* bVe     = (const float*)d_in[off + 13];
  const float* Un      = (const float*)d_in[off + 14];
  const float* bUn     = (const float*)d_in[off + 15];
  const float* Vn      = (const float*)d_in[off + 16];
  const float* bVn     = (const float*)d_in[off + 17];
  const float* g_e     = (const float*)d_in[off + 18];
  const float* be_bn   = (const float*)d_in[off + 19];
  const float* g_x     = (const float*)d_in[off + 20];
  const float* bx_bn   = (const float*)d_in[off + 21];
  const float* W_mlp1  = (const float*)d_in[off + 22];
  const float* b_mlp1  = (const float*)d_in[off + 23];
  const float* W_mlp2  = (const float*)d_in[off + 24];
  const float* b_mlp2  = (const float*)d_in[off + 25];

  char* ws = (char*)d_ws;
  float*  x       = (float*)(ws + 0x0000000);
  float2* VV      = (float2*)(ws + 0x0080000);   // 1 MB
  float*  Unx     = (float*)(ws + 0x0180000);    // 512 KB
  float*  aggN    = (float*)(ws + 0x0200000);    // 4 MB [8][BV][H]
  float*  aggD    = (float*)(ws + 0x0600000);    // 4 MB
  float*  bn_ps   = (float*)(ws + 0x0A00000);    // 4 MB
  float*  bn_ps2  = (float*)(ws + 0x0E00000);    // 4 MB
  float*  xtb     = (float*)(ws + 0x1200000);    // 512 KB
  float*  stats   = (float*)(ws + 0x1280000);    // Sx[3][256]+Se[2][256]+coef tables
  float*  out_acc = (float*)(ws + 0x1284000);
  bhalf*  UeT_g   = (bhalf*)(ws + 0x1290000);    // 96 KB
  bhalf*  t0      = (bhalf*)(ws + 0x1300000);                 // 64 MiB
  bhalf*  t1      = (bhalf*)(ws + 0x1300000 + 0x4000000);     // 64 MiB
  float*  Sx0 = stats;
  float*  Sx1 = stats + 256;
  float*  Sx2 = stats + 512;
  float*  Se0 = stats + 768;
  float*  Se1 = stats + 1024;
  float*  cEmb = stats + 1280;   // 384 floats: wa, wb, bc
  float*  cBN0 = stats + 1664;   // 256: sc0, sh0
  float*  cBN1 = stats + 1920;   // 256: sc1, sh1

  k0_all<<<BV_, 256, 0, stream>>>(x_coord, W_node, b_node, x, Ue, UeT_g,
                                  stats, out_acc, cEmb,
                                  W_eval, b_eval, W_ecat, b_ecat,
                                  Ve, bVe, Vn, bVn, Un, bUn, VV, Unx);

  const int G2 = BV_ * NJQ_;
  // ---- layer 0 ----
  k2_edge<0><<<G2, 256, 0, stream>>>(x_ev, x_tour, x_btour, cEmb,
                                     t0, (bhalf*)0, (bhalf*)0,
                                     UeT_g, bUe, VV, (float*)0, (float*)0,
                                     aggN, aggD, bn_ps, bn_ps2);
  kA<true><<<128, 256, 0, stream>>>(bn_ps, bn_ps2, Unx, aggN, aggD, xtb, Sx0, Se0);
  kB<0><<<BV_, 128, 0, stream>>>(x, xtb, Sx0, g_x, bx_bn,
                                 Ve + H_*H_, bVe + H_, Vn + H_*H_, bVn + H_,
                                 Un + H_*H_, bUn + H_, VV, Unx,
                                 (float*)0, (float*)0, (float*)0, (float*)0,
                                 out_acc, (float*)d_out,
                                 Se0, g_e, be_bn, cBN0);
  // ---- layer 1 ----
  k2_edge<1><<<G2, 256, 0, stream>>>(x_ev, x_tour, x_btour, cEmb,
                                     t1, t0, (bhalf*)0,
                                     UeT_g + H_*H_, bUe + H_, VV, cBN0, (float*)0,
                                     aggN, aggD, bn_ps, bn_ps2);
  kA<true><<<128, 256, 0, stream>>>(bn_ps, bn_ps2, Unx, aggN, aggD, xtb, Sx1, Se1);
  kB<0><<<BV_, 128, 0, stream>>>(x, xtb, Sx1, g_x + H_, bx_bn + H_,
                                 Ve + 2*H_*H_, bVe + 2*H_, Vn + 2*H_*H_, bVn + 2*H_,
                                 Un + 2*H_*H_, bUn + 2*H_, VV, Unx,
                                 (float*)0, (float*)0, (float*)0, (float*)0,
                                 out_acc, (float*)d_out,
                                 Se1, g_e + H_, be_bn + H_, cBN1);
  // ---- layer 2 ----
  k2_edge<2><<<G2, 256, 0, stream>>>(x_ev, x_tour, x_btour, cEmb,
                                     (bhalf*)0, t0, t1,
                                     UeT_g + 2*H_*H_, bUe + 2*H_, VV, cBN0, cBN1,
                                     aggN, aggD, bn_ps, bn_ps2);
  kA<false><<<64, 256, 0, stream>>>(bn_ps, bn_ps2, Unx, aggN, aggD, xtb, Sx2, Se0);
  kB<1><<<BV_, 128, 0, stream>>>(x, xtb, Sx2, g_x + 2*H_, bx_bn + 2*H_,
                                 (float*)0, (float*)0, (float*)0, (float*)0,
                                 (float*)0, (float*)0, VV, Unx,
                                 W_mlp1, b_mlp1, W_mlp2, b_mlp2,
                                 out_acc, (float*)d_out,
                                 (float*)0, (float*)0, (float*)0, (float*)0);
}